// Round 10
// baseline (576.873 us; speedup 1.0000x reference)
//
#include <hip/hip_runtime.h>
#include <hip/hip_bf16.h>

#define DD 256
#define BB 2048
#define NT 1024                  // tiles: 65536 c3-rows / 64 rows per tile

typedef __bf16 bf16x8 __attribute__((ext_vector_type(8)));
typedef float  f32x4  __attribute__((ext_vector_type(4)));

__device__ __forceinline__ unsigned short f2bf(float f) {
    unsigned int u = __float_as_uint(f);
    return (unsigned short)((u + 0x7FFFu + ((u >> 16) & 1u)) >> 16);  // RNE
}
__device__ __forceinline__ float bf2f(unsigned short s) {
    return __uint_as_float(((unsigned int)s) << 16);
}

// K1: rel = x - offsets (fp32 + bf16), one float4 per thread
__global__ void prep_rel(const float* __restrict__ x, const float* __restrict__ offsets,
                         float* __restrict__ rel_f32, unsigned short* __restrict__ rel_bf16) {
    const int fi = blockIdx.x * 256 + threadIdx.x;      // 131072 float4 groups
    const int d4 = fi & 63;
    const float4 o4 = ((const float4*)offsets)[d4];
    const float4 x4 = ((const float4*)x)[fi];
    float4 r;
    r.x = x4.x - o4.x; r.y = x4.y - o4.y; r.z = x4.z - o4.z; r.w = x4.w - o4.w;
    ((float4*)rel_f32)[fi] = r;
    ushort4 rb;
    rb.x = f2bf(r.x); rb.y = f2bf(r.y); rb.z = f2bf(r.z); rb.w = f2bf(r.w);
    ((ushort4*)rel_bf16)[fi] = rb;
}

// K3: barrier-free fused GEMM + c2 fold + in-wave weighted row reduction.
// Grid 1024 tiles (64 c3-rows each). 4 fully independent waves per block; each
// wave owns ALL 64 rows x full K=256 and a rotating set of 32-column chunks.
// B-fragments read directly from L2-resident rel_bf16 (1 MB) — no LDS, no syncs.
// NO __launch_bounds__: let the allocator pick a demand-driven VGPR/AGPR split
// (m97 precedent: 164+64). rj/c2 loads deferred past the K-loop to shrink the
// K-loop live set to afr(128)+acc(32)+bfr(8)+addr — the R9 spill fix.
__global__ void taylor3(
    const float* __restrict__ c3, const float* __restrict__ c2,
    const unsigned short* __restrict__ rel_bf16,
    float* __restrict__ partial)
{
    const int tile = blockIdx.x;
    const int i_t  = tile >> 2;          // i is constant across the 64-row tile
    const int jb   = (tile & 3) << 6;    // j window [jb, jb+64)
    const int lane = threadIdx.x & 63;
    const int wave = threadIdx.x >> 6;
    const int lrow = lane & 15, quad = lane >> 4;

    // ---- A fragments: 64 rows x 256 k, fp32->bf16 in-register (128 VGPRs) ----
    bf16x8 afr[8][4];
    {
        const float* abase = c3 + (size_t)tile * 64 * DD;
#pragma unroll
        for (int mt = 0; mt < 4; ++mt) {
            const float* p = abase + (size_t)(mt * 16 + lrow) * DD + quad * 8;
#pragma unroll
            for (int ks = 0; ks < 8; ++ks) {
                float4 f0 = *(const float4*)(p + ks * 32);
                float4 f1 = *(const float4*)(p + ks * 32 + 4);
                union { unsigned short u[8]; bf16x8 v; } cv;
                cv.u[0] = f2bf(f0.x); cv.u[1] = f2bf(f0.y);
                cv.u[2] = f2bf(f0.z); cv.u[3] = f2bf(f0.w);
                cv.u[4] = f2bf(f1.x); cv.u[5] = f2bf(f1.y);
                cv.u[6] = f2bf(f1.z); cv.u[7] = f2bf(f1.w);
                afr[ks][mt] = cv.v;
            }
        }
    }

    // ---- column-chunk loop: wave w -> chunks w, w+4, ..., 60 (no inter-wave deps) ----
    for (int cb = wave; cb < 64; cb += 4) {
        const int b0 = cb * 32;

        f32x4 acc[4][2];
#pragma unroll
        for (int mt = 0; mt < 4; ++mt)
#pragma unroll
            for (int nt = 0; nt < 2; ++nt)
                acc[mt][nt] = (f32x4){0.f, 0.f, 0.f, 0.f};

        // ---- K-loop: B-frags straight from global (16 rows x 64 B, coalesced) ----
#pragma unroll
        for (int ks = 0; ks < 8; ++ks) {
            bf16x8 bfr[2];
#pragma unroll
            for (int nt = 0; nt < 2; ++nt)
                bfr[nt] = *(const bf16x8*)(rel_bf16 +
                    (size_t)(b0 + nt * 16 + lrow) * DD + ks * 32 + quad * 8);
#pragma unroll
            for (int mt = 0; mt < 4; ++mt)
#pragma unroll
                for (int nt = 0; nt < 2; ++nt)
                    acc[mt][nt] = __builtin_amdgcn_mfma_f32_16x16x32_bf16(
                        afr[ks][mt], bfr[nt], acc[mt][nt], 0, 0, 0);
        }

        // ---- epilogue (loads issued only now — short live ranges) ----
        float sv[2];
#pragma unroll
        for (int nt = 0; nt < 2; ++nt) {
            const size_t rbase = (size_t)(b0 + nt * 16 + lrow) * DD;
            float s = 0.f;
#pragma unroll
            for (int mt = 0; mt < 4; ++mt) {
                const ushort4 r4 = *(const ushort4*)(rel_bf16 + rbase + jb + mt * 16 + quad * 4);
                const float4 c2r = *(const float4*)(c2 + (size_t)i_t * DD + jb + mt * 16 + quad * 4);
                s += (acc[mt][nt][0] + c2r.x) * bf2f(r4.x);
                s += (acc[mt][nt][1] + c2r.y) * bf2f(r4.y);
                s += (acc[mt][nt][2] + c2r.z) * bf2f(r4.z);
                s += (acc[mt][nt][3] + c2r.w) * bf2f(r4.w);
            }
            s += __shfl_xor(s, 16, 64);
            s += __shfl_xor(s, 32, 64);   // all quads now hold the full column sum
            sv[nt] = s;
        }
        if (lane < 32)   // col = b0 + lane; value from sv[lane>>4]
            partial[(size_t)tile * BB + b0 + lane] = (lane >> 4) ? sv[1] : sv[0];
    }
}

// K4: out[b] = c0 + <c1, rel_b> + sum_t rel[b, t>>2] * partial[t][b].
// 128 blocks x 256 threads; block covers 16 b's, 16 tile-slices of 64.
__global__ void reduce_partial(const float* __restrict__ partial,
                               const float* __restrict__ rel_f32,
                               const float* __restrict__ c0, const float* __restrict__ c1,
                               float* __restrict__ out) {
    __shared__ float red[256];
    const int t = threadIdx.x;
    const int bl = t & 15;                    // b within block's group of 16
    const int slice = t >> 4;                 // 16 slices x 64 tiles
    const int b = blockIdx.x * 16 + bl;
    float s = 0.f;
    for (int tl = slice * 64; tl < slice * 64 + 64; ++tl)
        s += rel_f32[(size_t)b * DD + (tl >> 2)] * partial[(size_t)tl * BB + b];
    float d = 0.f;                            // c1-dot chunk (16 elems per slice)
#pragma unroll
    for (int e = 0; e < 16; ++e) {
        const int k = slice * 16 + e;
        d += c1[k] * rel_f32[(size_t)b * DD + k];
    }
    red[t] = s + d;
    __syncthreads();
    if (t < 128) red[t] += red[t + 128]; __syncthreads();
    if (t < 64)  red[t] += red[t + 64];  __syncthreads();
    if (t < 32)  red[t] += red[t + 32];  __syncthreads();
    if (t < 16)  out[blockIdx.x * 16 + t] = c0[0] + red[t] + red[t + 16];
}

extern "C" void kernel_launch(void* const* d_in, const int* in_sizes, int n_in,
                              void* d_out, int out_size, void* d_ws, size_t ws_size,
                              hipStream_t stream) {
    const float* x       = (const float*)d_in[0];
    const float* offsets = (const float*)d_in[1];
    const float* c0      = (const float*)d_in[2];
    const float* c1      = (const float*)d_in[3];
    const float* c2      = (const float*)d_in[4];
    const float* c3      = (const float*)d_in[5];
    float* out = (float*)d_out;

    char* ws = (char*)d_ws;
    float* rel_f32 = (float*)ws;                                             // 2 MB
    unsigned short* rel_bf16 = (unsigned short*)(ws + (size_t)BB * DD * 4);  // 1 MB
    float* partial = (float*)(ws + (size_t)BB * DD * 6);                     // 8 MB (1024 x 2048)

    prep_rel<<<512, 256, 0, stream>>>(x, offsets, rel_f32, rel_bf16);
    taylor3<<<NT, 256, 0, stream>>>(c3, c2, rel_bf16, partial);
    reduce_partial<<<128, 256, 0, stream>>>(partial, rel_f32, c0, c1, out);
}

// Round 11
// 314.086 us; speedup vs baseline: 1.8367x; 1.8367x over previous
//
#include <hip/hip_runtime.h>
#include <hip/hip_bf16.h>

#define DD 256
#define BB 2048
#define NT 1024                  // tiles: (i, 64-wide j-window); 64 c3-rows each

typedef __bf16 bf16x8 __attribute__((ext_vector_type(8)));
typedef float  f32x4  __attribute__((ext_vector_type(4)));

__device__ __forceinline__ unsigned short f2bf(float f) {
    unsigned int u = __float_as_uint(f);
    return (unsigned short)((u + 0x7FFFu + ((u >> 16) & 1u)) >> 16);  // RNE
}
__device__ __forceinline__ float bf2f(unsigned short s) {
    return __uint_as_float(((unsigned int)s) << 16);
}

// K1: rel = x - offsets (fp32 + bf16), one float4 per thread
__global__ void prep_rel(const float* __restrict__ x, const float* __restrict__ offsets,
                         float* __restrict__ rel_f32, unsigned short* __restrict__ rel_bf16) {
    const int fi = blockIdx.x * 256 + threadIdx.x;      // 131072 float4 groups
    const int d4 = fi & 63;
    const float4 o4 = ((const float4*)offsets)[d4];
    const float4 x4 = ((const float4*)x)[fi];
    float4 r;
    r.x = x4.x - o4.x; r.y = x4.y - o4.y; r.z = x4.z - o4.z; r.w = x4.w - o4.w;
    ((float4*)rel_f32)[fi] = r;
    ushort4 rb;
    rb.x = f2bf(r.x); rb.y = f2bf(r.y); rb.z = f2bf(r.z); rb.w = f2bf(r.w);
    ((ushort4*)rel_bf16)[fi] = rb;
}

// K3: one-time-barrier fused GEMM + c2 fold + in-wave weighted row reduction.
// A-tile (64 c3-rows x 256 k, bf16) staged ONCE into LDS (XOR-swizzled granules),
// then 4 waves free-run over disjoint 64-col chunks — no per-stage barriers.
// K-loop live set ~80 arch regs (acc 64 -> AGPR; afr/bfr 16+16) — no spill at
// launch_bounds(256,2) (the R9/R10 spill killer).
__global__ __launch_bounds__(256, 2) void taylor3(
    const float* __restrict__ c3, const float* __restrict__ c2,
    const unsigned short* __restrict__ rel_bf16,
    float* __restrict__ partial)
{
    __shared__ unsigned short As[64 * DD];   // 32 KB

    const int tile = blockIdx.x;
    const int i_t  = tile >> 2;          // i constant across the tile
    const int jb   = (tile & 3) << 6;    // j window [jb, jb+64)
    const int tid  = threadIdx.x;
    const int lane = tid & 63;
    const int wave = tid >> 6;
    const int lrow = lane & 15, quad = lane >> 4;

    // ---- stage A: c3 tile fp32 -> bf16 -> LDS; granule g at phys g^(row&31) ----
    {
        const float* abase = c3 + (size_t)tile * 64 * DD;
#pragma unroll
        for (int rep = 0; rep < 8; ++rep) {
            const int gid = rep * 256 + tid;         // 2048 granules of 8 elems
            const int row = gid >> 5, g = gid & 31;
            const float4 f0 = *(const float4*)(abase + (size_t)row * DD + g * 8);
            const float4 f1 = *(const float4*)(abase + (size_t)row * DD + g * 8 + 4);
            union { unsigned short u[8]; uint4 v; } cv;
            cv.u[0] = f2bf(f0.x); cv.u[1] = f2bf(f0.y);
            cv.u[2] = f2bf(f0.z); cv.u[3] = f2bf(f0.w);
            cv.u[4] = f2bf(f1.x); cv.u[5] = f2bf(f1.y);
            cv.u[6] = f2bf(f1.z); cv.u[7] = f2bf(f1.w);
            const int phys = g ^ (row & 31);
            *(uint4*)(&As[row * DD + phys * 8]) = cv.v;
        }
    }
    __syncthreads();   // the ONLY barrier

    // ---- chunk loop: wave w -> 64-col chunks w, w+4, ..., w+28 ----
#pragma unroll 1
    for (int cb = wave; cb < 32; cb += 4) {
        const int b0 = cb * 64;

        f32x4 acc[4][4];
#pragma unroll
        for (int mt = 0; mt < 4; ++mt)
#pragma unroll
            for (int nt = 0; nt < 4; ++nt)
                acc[mt][nt] = (f32x4){0.f, 0.f, 0.f, 0.f};

        // ---- K-loop: A from LDS (swizzled, ~2-way max), B from L2-resident global ----
#pragma unroll
        for (int ks = 0; ks < 8; ++ks) {
            bf16x8 afr[4];
#pragma unroll
            for (int mt = 0; mt < 4; ++mt) {
                const int row = mt * 16 + lrow;
                const int phys = (ks * 4 + quad) ^ (row & 31);
                afr[mt] = *(const bf16x8*)(&As[row * DD + phys * 8]);
            }
            bf16x8 bfr[4];
#pragma unroll
            for (int nt = 0; nt < 4; ++nt)
                bfr[nt] = *(const bf16x8*)(rel_bf16 +
                    (size_t)(b0 + nt * 16 + lrow) * DD + ks * 32 + quad * 8);
#pragma unroll
            for (int mt = 0; mt < 4; ++mt)
#pragma unroll
                for (int nt = 0; nt < 4; ++nt)
                    acc[mt][nt] = __builtin_amdgcn_mfma_f32_16x16x32_bf16(
                        afr[mt], bfr[nt], acc[mt][nt], 0, 0, 0);
        }

        // ---- epilogue: s(col) = sum_rows (G + c2) * r[b, j(row)]; quad butterfly ----
        float sv[4];
#pragma unroll
        for (int nt = 0; nt < 4; ++nt) {
            const size_t rbase = (size_t)(b0 + nt * 16 + lrow) * DD;
            float s = 0.f;
#pragma unroll
            for (int mt = 0; mt < 4; ++mt) {
                const ushort4 r4 = *(const ushort4*)(rel_bf16 + rbase + jb + mt * 16 + quad * 4);
                const float4 c2r = *(const float4*)(c2 + (size_t)i_t * DD + jb + mt * 16 + quad * 4);
                s += (acc[mt][nt][0] + c2r.x) * bf2f(r4.x);
                s += (acc[mt][nt][1] + c2r.y) * bf2f(r4.y);
                s += (acc[mt][nt][2] + c2r.z) * bf2f(r4.z);
                s += (acc[mt][nt][3] + c2r.w) * bf2f(r4.w);
            }
            s += __shfl_xor(s, 16, 64);
            s += __shfl_xor(s, 32, 64);   // lanes with this lrow now hold col total
            sv[nt] = s;
        }
        // lane L writes col b0+L: nt = L>>4, value sv[L>>4] (select chain)
        const float v01 = (quad & 1) ? sv[1] : sv[0];
        const float v23 = (quad & 1) ? sv[3] : sv[2];
        partial[(size_t)tile * BB + b0 + lane] = (quad & 2) ? v23 : v01;
    }
}

// K4: out[b] = c0 + <c1, rel_b> + sum_t rel[b, t>>2] * partial[t][b].
// 128 blocks x 256 threads; block covers 16 b's, 16 tile-slices of 64.
__global__ void reduce_partial(const float* __restrict__ partial,
                               const float* __restrict__ rel_f32,
                               const float* __restrict__ c0, const float* __restrict__ c1,
                               float* __restrict__ out) {
    __shared__ float red[256];
    const int t = threadIdx.x;
    const int bl = t & 15;                    // b within block's group of 16
    const int slice = t >> 4;                 // 16 slices x 64 tiles
    const int b = blockIdx.x * 16 + bl;
    float s = 0.f;
    for (int tl = slice * 64; tl < slice * 64 + 64; ++tl)
        s += rel_f32[(size_t)b * DD + (tl >> 2)] * partial[(size_t)tl * BB + b];
    float d = 0.f;                            // c1-dot chunk (16 elems per slice)
#pragma unroll
    for (int e = 0; e < 16; ++e) {
        const int k = slice * 16 + e;
        d += c1[k] * rel_f32[(size_t)b * DD + k];
    }
    red[t] = s + d;
    __syncthreads();
    if (t < 128) red[t] += red[t + 128]; __syncthreads();
    if (t < 64)  red[t] += red[t + 64];  __syncthreads();
    if (t < 32)  red[t] += red[t + 32];  __syncthreads();
    if (t < 16)  out[blockIdx.x * 16 + t] = c0[0] + red[t] + red[t + 16];
}

extern "C" void kernel_launch(void* const* d_in, const int* in_sizes, int n_in,
                              void* d_out, int out_size, void* d_ws, size_t ws_size,
                              hipStream_t stream) {
    const float* x       = (const float*)d_in[0];
    const float* offsets = (const float*)d_in[1];
    const float* c0      = (const float*)d_in[2];
    const float* c1      = (const float*)d_in[3];
    const float* c2      = (const float*)d_in[4];
    const float* c3      = (const float*)d_in[5];
    float* out = (float*)d_out;

    char* ws = (char*)d_ws;
    float* rel_f32 = (float*)ws;                                             // 2 MB
    unsigned short* rel_bf16 = (unsigned short*)(ws + (size_t)BB * DD * 4);  // 1 MB
    float* partial = (float*)(ws + (size_t)BB * DD * 6);                     // 8 MB (1024 x 2048)

    prep_rel<<<512, 256, 0, stream>>>(x, offsets, rel_f32, rel_bf16);
    taylor3<<<NT, 256, 0, stream>>>(c3, c2, rel_bf16, partial);
    reduce_partial<<<128, 256, 0, stream>>>(partial, rel_f32, c0, c1, out);
}